// Round 1
// baseline (343.657 us; speedup 1.0000x reference)
//
#include <hip/hip_runtime.h>
#include <hip/hip_fp16.h>

typedef _Float16 f16;
typedef _Float16 half4 __attribute__((ext_vector_type(4)));
typedef _Float16 half8 __attribute__((ext_vector_type(8)));
typedef float f32x4 __attribute__((ext_vector_type(4)));

#define BATCH 16
#define L 1024
#define H 1024

// ---------------- W f32 -> fp16 ----------------
__global__ __launch_bounds__(256) void cvt_w(const float* __restrict__ W,
                                             f16* __restrict__ Wh) {
  const int i = (blockIdx.x * 256 + threadIdx.x) * 4;
  const float4 v = *(const float4*)(&W[i]);
  half4 h;
  h[0] = (f16)v.x; h[1] = (f16)v.y; h[2] = (f16)v.z; h[3] = (f16)v.w;
  *(half4*)(&Wh[i]) = h;
}

// ---------------- y [b,m,h] f32 -> Yt [b,h,m] fp16 ----------------
__global__ __launch_bounds__(256) void transpose_y(const float* __restrict__ Y,
                                                   f16* __restrict__ Yt) {
  __shared__ f16 tile[32][33];
  const int b = blockIdx.z;
  const float* Yb = Y + (long)b * L * H;
  f16* Ytb = Yt + (long)b * L * H;
  const int h0 = blockIdx.x * 32, m0 = blockIdx.y * 32;
  const int tx = threadIdx.x, ty = threadIdx.y;
  #pragma unroll
  for (int i = ty; i < 32; i += 8)
    tile[i][tx] = (f16)Yb[(long)(m0 + i) * H + h0 + tx];
  __syncthreads();
  #pragma unroll
  for (int i = ty; i < 32; i += 8)
    Ytb[(long)(h0 + i) * L + m0 + tx] = tile[tx][i];
}

// ---------------- GEMM: C[M,N] = A[M,K] * B[N,K]^T ----------------
// A: f32 (converted on the fly) or fp16; B: fp16 row-major [N,K].
// RELUB: C = fp16 relu(acc + bias[col]); else C = f32 acc.
constexpr int BM = 128, BN = 128, BK = 64;
constexpr int LDT = BK + 8;  // padded LDS row stride in halves (144 B)

template <bool AF32, bool RELUB>
__global__ __launch_bounds__(256) void gemm_tn(
    const void* __restrict__ Ap, const f16* __restrict__ Bp,
    const float* __restrict__ bias, void* __restrict__ Cp,
    int M, int N, int K, long sA, long sB, long sC) {
  __shared__ f16 shA[BM * LDT];
  __shared__ f16 shB[BN * LDT];
  const int tid = threadIdx.x;
  const int lane = tid & 63;
  const int wid = tid >> 6;
  const int wr = (wid >> 1) * 64;
  const int wc = (wid & 1) * 64;
  const long zb = blockIdx.z;
  const int row0 = blockIdx.y * BM;
  const int col0 = blockIdx.x * BN;

  const f16* B = Bp + zb * sB;

  f32x4 acc[4][4];
  #pragma unroll
  for (int i = 0; i < 4; ++i)
    #pragma unroll
    for (int j = 0; j < 4; ++j)
      acc[i][j] = (f32x4){0.f, 0.f, 0.f, 0.f};

  for (int kt = 0; kt < K; kt += BK) {
    if (AF32) {
      const float* A = (const float*)Ap + zb * sA;
      const int c4 = (tid & 15) * 4;
      const int r0 = tid >> 4;
      #pragma unroll
      for (int it = 0; it < 8; ++it) {
        const int r = it * 16 + r0;
        const float4 v = *(const float4*)(&A[(long)(row0 + r) * K + kt + c4]);
        half4 h;
        h[0] = (f16)v.x; h[1] = (f16)v.y; h[2] = (f16)v.z; h[3] = (f16)v.w;
        *(half4*)(&shA[r * LDT + c4]) = h;
      }
    } else {
      const f16* A = (const f16*)Ap + zb * sA;
      const int c8 = (tid & 7) * 8;
      const int r0 = tid >> 3;
      #pragma unroll
      for (int it = 0; it < 4; ++it) {
        const int r = it * 32 + r0;
        *(half8*)(&shA[r * LDT + c8]) =
            *(const half8*)(&A[(long)(row0 + r) * K + kt + c8]);
      }
    }
    {
      const int c8 = (tid & 7) * 8;
      const int r0 = tid >> 3;
      #pragma unroll
      for (int it = 0; it < 4; ++it) {
        const int r = it * 32 + r0;
        *(half8*)(&shB[r * LDT + c8]) =
            *(const half8*)(&B[(long)(col0 + r) * K + kt + c8]);
      }
    }
    __syncthreads();
    #pragma unroll
    for (int ks = 0; ks < 2; ++ks) {
      const int ko = ks * 32 + (lane >> 4) * 8;
      half8 af[4], bf[4];
      #pragma unroll
      for (int i = 0; i < 4; ++i)
        af[i] = *(const half8*)(&shA[(wr + i * 16 + (lane & 15)) * LDT + ko]);
      #pragma unroll
      for (int j = 0; j < 4; ++j)
        bf[j] = *(const half8*)(&shB[(wc + j * 16 + (lane & 15)) * LDT + ko]);
      #pragma unroll
      for (int i = 0; i < 4; ++i)
        #pragma unroll
        for (int j = 0; j < 4; ++j)
          acc[i][j] = __builtin_amdgcn_mfma_f32_16x16x32_f16(af[i], bf[j],
                                                             acc[i][j], 0, 0, 0);
    }
    __syncthreads();
  }

  if (RELUB) {
    f16* C = (f16*)Cp + zb * sC;
    #pragma unroll
    for (int j = 0; j < 4; ++j) {
      const int col = col0 + wc + j * 16 + (lane & 15);
      const float bv = bias[col];
      #pragma unroll
      for (int i = 0; i < 4; ++i) {
        const int rowb = row0 + wr + i * 16 + (lane >> 4) * 4;
        #pragma unroll
        for (int r = 0; r < 4; ++r) {
          float v = acc[i][j][r] + bv;
          v = v > 0.f ? v : 0.f;
          C[(long)(rowb + r) * N + col] = (f16)v;
        }
      }
    }
  } else {
    float* C = (float*)Cp + zb * sC;
    #pragma unroll
    for (int j = 0; j < 4; ++j) {
      const int col = col0 + wc + j * 16 + (lane & 15);
      #pragma unroll
      for (int i = 0; i < 4; ++i) {
        const int rowb = row0 + wr + i * 16 + (lane >> 4) * 4;
        #pragma unroll
        for (int r = 0; r < 4; ++r)
          C[(long)(rowb + r) * N + col] = acc[i][j][r];
      }
    }
  }
}

// ---------------- masked row softmax: f32 scores -> fp16 alpha ----------------
__global__ __launch_bounds__(256) void softmax_rows(const float* __restrict__ S,
                                                    const int* __restrict__ mask,
                                                    f16* __restrict__ P) {
  const int b = blockIdx.y;
  const int l = blockIdx.x;
  const float* srow = S + ((long)b * L + l) * L;
  f16* prow = P + ((long)b * L + l) * L;
  const int* mrow = mask + b * L;
  const int t = threadIdx.x;

  const float4 v = *(const float4*)(&srow[t * 4]);
  const int4 mk = *(const int4*)(&mrow[t * 4]);
  const float x0 = mk.x ? -1e30f : v.x;
  const float x1 = mk.y ? -1e30f : v.y;
  const float x2 = mk.z ? -1e30f : v.z;
  const float x3 = mk.w ? -1e30f : v.w;

  float mx = fmaxf(fmaxf(x0, x1), fmaxf(x2, x3));
  #pragma unroll
  for (int off = 32; off >= 1; off >>= 1)
    mx = fmaxf(mx, __shfl_xor(mx, off));
  __shared__ float red[8];
  const int wid = t >> 6, lane = t & 63;
  if (lane == 0) red[wid] = mx;
  __syncthreads();
  mx = fmaxf(fmaxf(red[0], red[1]), fmaxf(red[2], red[3]));

  const float e0 = __expf(x0 - mx), e1 = __expf(x1 - mx);
  const float e2 = __expf(x2 - mx), e3 = __expf(x3 - mx);
  float s = e0 + e1 + e2 + e3;
  #pragma unroll
  for (int off = 32; off >= 1; off >>= 1)
    s += __shfl_xor(s, off);
  if (lane == 0) red[4 + wid] = s;
  __syncthreads();
  s = red[4] + red[5] + red[6] + red[7];
  const float inv = 1.f / s;
  half4 h;
  h[0] = (f16)(e0 * inv); h[1] = (f16)(e1 * inv);
  h[2] = (f16)(e2 * inv); h[3] = (f16)(e3 * inv);
  *(half4*)(&prow[t * 4]) = h;
}

extern "C" void kernel_launch(void* const* d_in, const int* in_sizes, int n_in,
                              void* d_out, int out_size, void* d_ws,
                              size_t ws_size, hipStream_t stream) {
  const float* x = (const float*)d_in[0];
  const float* y = (const float*)d_in[1];
  const int* ymask = (const int*)d_in[2];
  const float* W = (const float*)d_in[3];
  const float* bias = (const float*)d_in[4];
  float* out = (float*)d_out;

  char* ws = (char*)d_ws;
  f16* Wh = (f16*)(ws);                                   // 2 MB
  f16* Yt = (f16*)(ws + (1L << 21));                      // 32 MB
  f16* Xp = (f16*)(ws + (1L << 21) + (1L << 25));         // 32 MB
  f16* Yp = (f16*)(ws + (1L << 21) + 2 * (1L << 25));     // 32 MB
  float* Sc = (float*)(ws + (1L << 21) + 3 * (1L << 25)); // 64 MB
  f16* Alpha = Xp;  // Xp dead after scores GEMM

  cvt_w<<<1024, 256, 0, stream>>>(W, Wh);
  transpose_y<<<dim3(32, 32, BATCH), dim3(32, 8), 0, stream>>>(y, Yt);

  // projections: [16384,1024] = relu(in @ W^T + b), fp16 out
  gemm_tn<true, true><<<dim3(8, 128, 1), 256, 0, stream>>>(
      x, Wh, bias, Xp, BATCH * L, H, H, 0, 0, 0);
  gemm_tn<true, true><<<dim3(8, 128, 1), 256, 0, stream>>>(
      y, Wh, bias, Yp, BATCH * L, H, H, 0, 0, 0);

  // scores[b] = Xp[b] @ Yp[b]^T, f32
  gemm_tn<false, false><<<dim3(8, 8, BATCH), 256, 0, stream>>>(
      Xp, Yp, nullptr, Sc, L, L, H, (long)L * H, (long)L * H, (long)L * L);

  // alpha = softmax(mask(scores)), fp16 (into Xp region)
  softmax_rows<<<dim3(L, BATCH), 256, 0, stream>>>(Sc, ymask, Alpha);

  // out[b] = alpha[b] @ Yt[b]^T  (Yt is [h,m] so this is alpha @ y)
  gemm_tn<false, false><<<dim3(8, 8, BATCH), 256, 0, stream>>>(
      Alpha, Yt, nullptr, out, L, H, L, (long)L * L, (long)H * L, (long)L * H);
}

// Round 2
// 259.273 us; speedup vs baseline: 1.3255x; 1.3255x over previous
//
#include <hip/hip_runtime.h>
#include <hip/hip_fp16.h>

typedef _Float16 f16;
typedef _Float16 half4 __attribute__((ext_vector_type(4)));
typedef _Float16 half8 __attribute__((ext_vector_type(8)));
typedef float f32x4 __attribute__((ext_vector_type(4)));

#define BATCH 16
#define L 1024
#define H 1024

// ---------------- f32 -> fp16 bulk convert (8 elems/thread) ----------------
__global__ __launch_bounds__(256) void cvt_f32_f16(const float* __restrict__ in,
                                                   f16* __restrict__ out, long n) {
  long i = ((long)blockIdx.x * 256 + threadIdx.x) * 8;
  const long stride = (long)gridDim.x * 256 * 8;
  for (; i < n; i += stride) {
    const float4 a = *(const float4*)(&in[i]);
    const float4 b = *(const float4*)(&in[i + 4]);
    half8 h;
    h[0] = (f16)a.x; h[1] = (f16)a.y; h[2] = (f16)a.z; h[3] = (f16)a.w;
    h[4] = (f16)b.x; h[5] = (f16)b.y; h[6] = (f16)b.z; h[7] = (f16)b.w;
    *(half8*)(&out[i]) = h;
  }
}

// ------- y [b,m,h] f32 -> Yh [b,m,h] fp16 AND Yt [b,h,m] fp16 -------
__global__ __launch_bounds__(256) void transpose_y(const float* __restrict__ Y,
                                                   f16* __restrict__ Yh,
                                                   f16* __restrict__ Yt) {
  __shared__ f16 tile[32][33];
  const int b = blockIdx.z;
  const float* Yb = Y + (long)b * L * H;
  f16* Yhb = Yh + (long)b * L * H;
  f16* Ytb = Yt + (long)b * L * H;
  const int h0 = blockIdx.x * 32, m0 = blockIdx.y * 32;
  const int tx = threadIdx.x, ty = threadIdx.y;
  #pragma unroll
  for (int i = ty; i < 32; i += 8) {
    const f16 hv = (f16)Yb[(long)(m0 + i) * H + h0 + tx];
    tile[i][tx] = hv;
    Yhb[(long)(m0 + i) * H + h0 + tx] = hv;
  }
  __syncthreads();
  #pragma unroll
  for (int i = ty; i < 32; i += 8)
    Ytb[(long)(h0 + i) * L + m0 + tx] = tile[tx][i];
}

// ---------------- GEMM: C[M,N] = A[M,K] * B[N,K]^T  (fp16 in) ----------------
// m97 structure: global_load_lds width-16 staging, linear LDS + XOR slot
// swizzle (slot ^= row&7, 16B slots within each 128B row), 2-barrier K-loop.
// EPI 0: C = fp16 relu(acc + bias[col]);  EPI 1: C = f32 acc.
constexpr int BM = 128, BN = 128, BK = 64;

template <int EPI>
__global__ __launch_bounds__(256) void gemm_tn(
    const f16* __restrict__ Ap, const f16* __restrict__ Bp,
    const float* __restrict__ bias, void* __restrict__ Cp,
    int N, int K, long sA, long sB, long sC, int nxy_shift) {
  __shared__ f16 shA[BM * BK];
  __shared__ f16 shB[BN * BK];
  const int tid = threadIdx.x;
  const int lane = tid & 63;
  const int wid = tid >> 6;

  // XCD-aware bijective swizzle (nwg % 8 == 0 for all our launches)
  const int nwg = gridDim.x;
  const int q = nwg >> 3;
  const int orig = blockIdx.x;
  const int wg = (orig & 7) * q + (orig >> 3);
  const int bz = wg >> nxy_shift;
  const int rxy = wg & ((1 << nxy_shift) - 1);
  const int bx = rxy & 7, by = rxy >> 3;
  const int row0 = by * BM, col0 = bx * BN;

  const f16* A = Ap + (long)bz * sA;
  const f16* B = Bp + (long)bz * sB;

  // staging: chunk c = 1KB = 8 rows x 128B; lane l covers row c*8+(l>>3),
  // 16B slot ((l&7) ^ (l>>3))  [inverse of the read-side XOR swizzle]
  const int srow = lane >> 3;
  const int scol16 = (lane & 7) ^ srow;

  f32x4 acc[4][4];
  #pragma unroll
  for (int i = 0; i < 4; ++i)
    #pragma unroll
    for (int j = 0; j < 4; ++j)
      acc[i][j] = (f32x4){0.f, 0.f, 0.f, 0.f};

  const int wr = (wid >> 1) * 64, wc = (wid & 1) * 64;
  const int fr = lane & 15, fq = lane >> 4;

  for (int kt = 0; kt < K; kt += BK) {
    #pragma unroll
    for (int ci = 0; ci < 4; ++ci) {
      const int c = ci * 4 + wid;  // wave-uniform chunk id
      const long arow = row0 + c * 8 + srow;
      const f16* ga = A + arow * (long)K + kt + scol16 * 8;
      __builtin_amdgcn_global_load_lds(
          (const __attribute__((address_space(1))) void*)ga,
          (__attribute__((address_space(3))) void*)&shA[c * 512], 16, 0, 0);
      const long brow = col0 + c * 8 + srow;
      const f16* gb = B + brow * (long)K + kt + scol16 * 8;
      __builtin_amdgcn_global_load_lds(
          (const __attribute__((address_space(1))) void*)gb,
          (__attribute__((address_space(3))) void*)&shB[c * 512], 16, 0, 0);
    }
    __syncthreads();
    #pragma unroll
    for (int ks = 0; ks < 2; ++ks) {
      const int slot = (4 * ks + fq) ^ (lane & 7);  // == read XOR (row&7)
      half8 af[4], bf[4];
      #pragma unroll
      for (int i = 0; i < 4; ++i) {
        const int rowa = wr + i * 16 + fr;
        af[i] = *(const half8*)((const char*)shA + rowa * 128 + slot * 16);
      }
      #pragma unroll
      for (int j = 0; j < 4; ++j) {
        const int rowb = wc + j * 16 + fr;
        bf[j] = *(const half8*)((const char*)shB + rowb * 128 + slot * 16);
      }
      #pragma unroll
      for (int i = 0; i < 4; ++i)
        #pragma unroll
        for (int j = 0; j < 4; ++j)
          acc[i][j] = __builtin_amdgcn_mfma_f32_16x16x32_f16(af[i], bf[j],
                                                             acc[i][j], 0, 0, 0);
    }
    __syncthreads();
  }

  if (EPI == 0) {
    f16* C = (f16*)Cp + (long)bz * sC;
    #pragma unroll
    for (int j = 0; j < 4; ++j) {
      const int col = col0 + wc + j * 16 + fr;
      const float bv = bias[col];
      #pragma unroll
      for (int i = 0; i < 4; ++i) {
        const int rowb = row0 + wr + i * 16 + fq * 4;
        #pragma unroll
        for (int r = 0; r < 4; ++r) {
          float v = acc[i][j][r] + bv;
          v = v > 0.f ? v : 0.f;
          C[(long)(rowb + r) * N + col] = (f16)v;
        }
      }
    }
  } else {
    float* C = (float*)Cp + (long)bz * sC;
    #pragma unroll
    for (int j = 0; j < 4; ++j) {
      const int col = col0 + wc + j * 16 + fr;
      #pragma unroll
      for (int i = 0; i < 4; ++i) {
        const int rowb = row0 + wr + i * 16 + fq * 4;
        #pragma unroll
        for (int r = 0; r < 4; ++r)
          C[(long)(rowb + r) * N + col] = acc[i][j][r];
      }
    }
  }
}

// ---------------- masked row softmax: f32 scores -> fp16 alpha ----------------
__global__ __launch_bounds__(256) void softmax_rows(const float* __restrict__ S,
                                                    const int* __restrict__ mask,
                                                    f16* __restrict__ P) {
  const int b = blockIdx.y;
  const int l = blockIdx.x;
  const float* srow = S + ((long)b * L + l) * L;
  f16* prow = P + ((long)b * L + l) * L;
  const int* mrow = mask + b * L;
  const int t = threadIdx.x;

  const float4 v = *(const float4*)(&srow[t * 4]);
  const int4 mk = *(const int4*)(&mrow[t * 4]);
  const float x0 = mk.x ? -1e30f : v.x;
  const float x1 = mk.y ? -1e30f : v.y;
  const float x2 = mk.z ? -1e30f : v.z;
  const float x3 = mk.w ? -1e30f : v.w;

  float mx = fmaxf(fmaxf(x0, x1), fmaxf(x2, x3));
  #pragma unroll
  for (int off = 32; off >= 1; off >>= 1)
    mx = fmaxf(mx, __shfl_xor(mx, off));
  __shared__ float red[8];
  const int wid = t >> 6, lane = t & 63;
  if (lane == 0) red[wid] = mx;
  __syncthreads();
  mx = fmaxf(fmaxf(red[0], red[1]), fmaxf(red[2], red[3]));

  const float e0 = __expf(x0 - mx), e1 = __expf(x1 - mx);
  const float e2 = __expf(x2 - mx), e3 = __expf(x3 - mx);
  float s = e0 + e1 + e2 + e3;
  #pragma unroll
  for (int off = 32; off >= 1; off >>= 1)
    s += __shfl_xor(s, off);
  if (lane == 0) red[4 + wid] = s;
  __syncthreads();
  s = red[4] + red[5] + red[6] + red[7];
  const float inv = 1.f / s;
  half4 h;
  h[0] = (f16)(e0 * inv); h[1] = (f16)(e1 * inv);
  h[2] = (f16)(e2 * inv); h[3] = (f16)(e3 * inv);
  *(half4*)(&prow[t * 4]) = h;
}

extern "C" void kernel_launch(void* const* d_in, const int* in_sizes, int n_in,
                              void* d_out, int out_size, void* d_ws,
                              size_t ws_size, hipStream_t stream) {
  const float* x = (const float*)d_in[0];
  const float* y = (const float*)d_in[1];
  const int* ymask = (const int*)d_in[2];
  const float* W = (const float*)d_in[3];
  const float* bias = (const float*)d_in[4];
  float* out = (float*)d_out;

  // ws layout (162 MB):
  //   Wh   2 MB | Yt  32 MB | XYp 64 MB | XYh 64 MB (aliased by Sc after proj)
  char* ws = (char*)d_ws;
  f16* Wh = (f16*)(ws);
  f16* Yt = (f16*)(ws + (1L << 21));
  f16* XYp = (f16*)(ws + (1L << 21) + (1L << 25));
  f16* XYh = (f16*)(ws + (1L << 21) + (1L << 25) + (1L << 26));
  float* Sc = (float*)XYh;       // XYh dead after proj GEMM
  f16* Alpha = XYp;              // Xp half dead after scores GEMM

  f16* Xh = XYh;                 // rows [0, 16384)
  f16* Yh = XYh + (long)BATCH * L * H;  // rows [16384, 32768)

  cvt_f32_f16<<<512, 256, 0, stream>>>(W, Wh, (long)H * H);
  cvt_f32_f16<<<8192, 256, 0, stream>>>(x, Xh, (long)BATCH * L * H);
  transpose_y<<<dim3(32, 32, BATCH), dim3(32, 8), 0, stream>>>(y, Yh, Yt);

  // fused projection: [32768,1024] = relu(XYh @ Wh^T + b), fp16
  gemm_tn<0><<<2048, 256, 0, stream>>>(XYh, Wh, bias, XYp,
                                       H, H, 0, 0, 0, 11);

  // scores[b] = Xp[b] @ Yp[b]^T, f32
  gemm_tn<1><<<1024, 256, 0, stream>>>(XYp, XYp + (long)BATCH * L * H, nullptr,
                                       Sc, L, H, (long)L * H, (long)L * H,
                                       (long)L * L, 6);

  // alpha = softmax(mask(scores)), fp16 (into dead Xp region)
  softmax_rows<<<dim3(L, BATCH), 256, 0, stream>>>(Sc, ymask, Alpha);

  // out[b] = alpha[b] @ Yt[b]^T  == alpha[b] @ y[b]
  gemm_tn<1><<<1024, 256, 0, stream>>>(Alpha, Yt, nullptr, out,
                                       H, L, (long)L * L, (long)H * L,
                                       (long)L * H, 6);
}

// Round 3
// 242.514 us; speedup vs baseline: 1.4171x; 1.0691x over previous
//
#include <hip/hip_runtime.h>
#include <hip/hip_fp16.h>

typedef _Float16 f16;
typedef _Float16 half4 __attribute__((ext_vector_type(4)));
typedef _Float16 half8 __attribute__((ext_vector_type(8)));
typedef float f32x4 __attribute__((ext_vector_type(4)));

#define BATCH 16
#define L 1024
#define H 1024

// ---------------- f32 -> fp16 bulk convert (8 elems/thread) ----------------
__global__ __launch_bounds__(256) void cvt_f32_f16(const float* __restrict__ in,
                                                   f16* __restrict__ out, long n) {
  long i = ((long)blockIdx.x * 256 + threadIdx.x) * 8;
  const long stride = (long)gridDim.x * 256 * 8;
  for (; i < n; i += stride) {
    const float4 a = *(const float4*)(&in[i]);
    const float4 b = *(const float4*)(&in[i + 4]);
    half8 h;
    h[0] = (f16)a.x; h[1] = (f16)a.y; h[2] = (f16)a.z; h[3] = (f16)a.w;
    h[4] = (f16)b.x; h[5] = (f16)b.y; h[6] = (f16)b.z; h[7] = (f16)b.w;
    *(half8*)(&out[i]) = h;
  }
}

// ------- y [b,m,h] f32 -> Yh [b,m,h] fp16 AND Yt [b,h,m] fp16 -------
__global__ __launch_bounds__(256) void transpose_y(const float* __restrict__ Y,
                                                   f16* __restrict__ Yh,
                                                   f16* __restrict__ Yt) {
  __shared__ f16 tile[32][33];
  const int b = blockIdx.z;
  const float* Yb = Y + (long)b * L * H;
  f16* Yhb = Yh + (long)b * L * H;
  f16* Ytb = Yt + (long)b * L * H;
  const int h0 = blockIdx.x * 32, m0 = blockIdx.y * 32;
  const int tx = threadIdx.x, ty = threadIdx.y;
  #pragma unroll
  for (int i = ty; i < 32; i += 8) {
    const f16 hv = (f16)Yb[(long)(m0 + i) * H + h0 + tx];
    tile[i][tx] = hv;
    Yhb[(long)(m0 + i) * H + h0 + tx] = hv;
  }
  __syncthreads();
  #pragma unroll
  for (int i = ty; i < 32; i += 8)
    Ytb[(long)(h0 + i) * L + m0 + tx] = tile[tx][i];
}

// =====================================================================
// 256x256 tile GEMM, BK=32, 8 waves, triple-buffered LDS, counted vmcnt.
// C[M,N=1024] = A[M,K=1024] * B[N,K]^T, fp16 in, EPI0: fp16 relu(+bias),
// EPI1: f32.  Schedule per K-tile t (2 phases):
//   P1: issue 2 gload_lds (tile t+2, A-chunks) | ds_read A(mh0)x4 + Bx4
//       | bar | prio1 | 16 MFMA | prio0 | bar
//   P2: issue 2 gload_lds (tile t+2, B-chunks) | ds_read A(mh1)x4
//       | bar | prio1 | 16 MFMA | prio0 | vmcnt(4) | bar
// vmcnt(4) at boundary: oldest 4 (tile t+1, issued during t-1) landed;
// newest 4 (t+2) stay in flight across the barrier. Buffer (t+2)%3 was
// last read before the t-1 -> t barrier, which all waves passed.
// =====================================================================
constexpr int TBK = 32;

#define GLD16(g, l)                                           \
  __builtin_amdgcn_global_load_lds(                           \
      (const __attribute__((address_space(1))) void*)(g),     \
      (__attribute__((address_space(3))) void*)(l), 16, 0, 0)

template <int EPI>
__global__ __launch_bounds__(512, 2) void gemm256(
    const f16* __restrict__ Ap, const f16* __restrict__ Bp,
    const float* __restrict__ bias, void* __restrict__ Cp,
    long sA, long sB, long sC, int nxyShift) {
  __shared__ f16 lds[3 * 16384];  // 3 bufs x (A 16KB + B 16KB) = 96 KB
  constexpr int N = 1024, K = 1024, NT = K / TBK;

  const int tid = threadIdx.x;
  const int lane = tid & 63;
  const int wid = tid >> 6;   // 0..7
  const int wm = wid >> 2;    // 0..1  (M half)
  const int wn = wid & 3;     // 0..3  (N quarter)

  // XCD-aware bijective swizzle (nwg % 8 == 0 for all launches)
  const int nwg = gridDim.x;
  const int orig = blockIdx.x;
  const int wg = (orig & 7) * (nwg >> 3) + (orig >> 3);
  const int bz = wg >> nxyShift;
  const int rxy = wg & ((1 << nxyShift) - 1);
  const int bx = rxy & 3;      // N=1024 -> 4 col blocks
  const int by = rxy >> 2;
  const int row0 = by * 256, col0 = bx * 256;

  const f16* A = Ap + (long)bz * sA;
  const f16* B = Bp + (long)bz * sB;

  // ---- staging addressing (chunk = 16 rows x 64B = 1KB) ----
  const int srow = lane >> 2;                       // row in chunk
  const int sslot = (lane & 3) ^ ((lane >> 3) & 3); // pre-swizzled src slot
  const int ca0 = wid * 2, ca1 = wid * 2 + 1;       // this wave's chunks
  const f16* gA0 = A + (long)(row0 + ca0 * 16 + srow) * K + sslot * 8;
  const f16* gA1 = A + (long)(row0 + ca1 * 16 + srow) * K + sslot * 8;
  const f16* gB0 = B + (long)(col0 + ca0 * 16 + srow) * K + sslot * 8;
  const f16* gB1 = B + (long)(col0 + ca1 * 16 + srow) * K + sslot * 8;
  char* ldsw = (char*)lds;

  // ---- fragment read addressing (read-side XOR matches staging) ----
  const int fr = lane & 15, fq = lane >> 4;
  const int rsw = (fq ^ ((fr >> 1) & 3)) << 4;      // swizzled 16B slot
  const int aByte = (wm * 128 + fr) * 64 + rsw;
  const int bByte = (wn * 64 + fr) * 64 + rsw;
  const char* ldsr = (const char*)lds;

  f32x4 acc[8][4];
  #pragma unroll
  for (int i = 0; i < 8; ++i)
    #pragma unroll
    for (int j = 0; j < 4; ++j)
      acc[i][j] = (f32x4){0.f, 0.f, 0.f, 0.f};

  // ---- prologue: stage tile0 -> buf0, tile1 -> buf1 ----
  GLD16(gA0, ldsw + ca0 * 1024);
  GLD16(gA1, ldsw + ca1 * 1024);
  GLD16(gB0, ldsw + 16384 + ca0 * 1024);
  GLD16(gB1, ldsw + 16384 + ca1 * 1024);
  GLD16(gA0 + TBK, ldsw + 32768 + ca0 * 1024);
  GLD16(gA1 + TBK, ldsw + 32768 + ca1 * 1024);
  GLD16(gB0 + TBK, ldsw + 32768 + 16384 + ca0 * 1024);
  GLD16(gB1 + TBK, ldsw + 32768 + 16384 + ca1 * 1024);
  gA0 += 2 * TBK; gA1 += 2 * TBK; gB0 += 2 * TBK; gB1 += 2 * TBK;

  asm volatile("s_waitcnt vmcnt(4)" ::: "memory");
  __builtin_amdgcn_s_barrier();
  __builtin_amdgcn_sched_barrier(0);

  int cbB = 0;          // compute-buffer byte offset
  int pbB = 2 * 32768;  // prefetch-buffer byte offset

  for (int t = 0; t < NT; ++t) {
    const bool pf = (t + 2) < NT;
    const char* base = ldsr + cbB;
    // ---------------- phase 1 (mh = 0) ----------------
    if (pf) {
      GLD16(gA0, ldsw + pbB + ca0 * 1024);
      GLD16(gA1, ldsw + pbB + ca1 * 1024);
    }
    half8 av[4], bv[4];
    #pragma unroll
    for (int i = 0; i < 4; ++i)
      av[i] = *(const half8*)(base + aByte + i * 1024);
    #pragma unroll
    for (int j = 0; j < 4; ++j)
      bv[j] = *(const half8*)(base + 16384 + bByte + j * 1024);
    __builtin_amdgcn_sched_barrier(0);
    __builtin_amdgcn_s_barrier();
    __builtin_amdgcn_sched_barrier(0);
    __builtin_amdgcn_s_setprio(1);
    #pragma unroll
    for (int i = 0; i < 4; ++i)
      #pragma unroll
      for (int j = 0; j < 4; ++j)
        acc[i][j] = __builtin_amdgcn_mfma_f32_16x16x32_f16(av[i], bv[j],
                                                           acc[i][j], 0, 0, 0);
    __builtin_amdgcn_s_setprio(0);
    __builtin_amdgcn_sched_barrier(0);
    __builtin_amdgcn_s_barrier();
    __builtin_amdgcn_sched_barrier(0);
    // ---------------- phase 2 (mh = 1) ----------------
    if (pf) {
      GLD16(gB0, ldsw + pbB + 16384 + ca0 * 1024);
      GLD16(gB1, ldsw + pbB + 16384 + ca1 * 1024);
      gA0 += TBK; gA1 += TBK; gB0 += TBK; gB1 += TBK;
    }
    #pragma unroll
    for (int i = 0; i < 4; ++i)
      av[i] = *(const half8*)(base + aByte + 4096 + i * 1024);
    __builtin_amdgcn_sched_barrier(0);
    __builtin_amdgcn_s_barrier();
    __builtin_amdgcn_sched_barrier(0);
    __builtin_amdgcn_s_setprio(1);
    #pragma unroll
    for (int i = 0; i < 4; ++i)
      #pragma unroll
      for (int j = 0; j < 4; ++j)
        acc[4 + i][j] = __builtin_amdgcn_mfma_f32_16x16x32_f16(av[i], bv[j],
                                                               acc[4 + i][j],
                                                               0, 0, 0);
    __builtin_amdgcn_s_setprio(0);
    __builtin_amdgcn_sched_barrier(0);
    if (t + 2 < NT) {
      asm volatile("s_waitcnt vmcnt(4)" ::: "memory");
    } else if (t + 1 < NT) {
      asm volatile("s_waitcnt vmcnt(0)" ::: "memory");
    }
    __builtin_amdgcn_s_barrier();
    __builtin_amdgcn_sched_barrier(0);
    cbB = (cbB == 65536) ? 0 : cbB + 32768;
    pbB = (pbB == 65536) ? 0 : pbB + 32768;
  }

  // ---------------- epilogue ----------------
  if (EPI == 0) {
    f16* C = (f16*)Cp + (long)bz * sC;
    #pragma unroll
    for (int j = 0; j < 4; ++j) {
      const int col = col0 + wn * 64 + j * 16 + fr;
      const float bvs = bias[col];
      #pragma unroll
      for (int i = 0; i < 8; ++i) {
        const int rowb = row0 + wm * 128 + i * 16 + fq * 4;
        #pragma unroll
        for (int r = 0; r < 4; ++r) {
          float v = acc[i][j][r] + bvs;
          v = v > 0.f ? v : 0.f;
          C[(long)(rowb + r) * N + col] = (f16)v;
        }
      }
    }
  } else {
    float* C = (float*)Cp + (long)bz * sC;
    #pragma unroll
    for (int j = 0; j < 4; ++j) {
      const int col = col0 + wn * 64 + j * 16 + fr;
      #pragma unroll
      for (int i = 0; i < 8; ++i) {
        const int rowb = row0 + wm * 128 + i * 16 + fq * 4;
        #pragma unroll
        for (int r = 0; r < 4; ++r)
          C[(long)(rowb + r) * N + col] = acc[i][j][r];
      }
    }
  }
}

// ---------------- masked row softmax: f32 scores -> fp16 alpha ----------------
__global__ __launch_bounds__(256) void softmax_rows(const float* __restrict__ S,
                                                    const int* __restrict__ mask,
                                                    f16* __restrict__ P) {
  const int b = blockIdx.y;
  const int l = blockIdx.x;
  const float* srow = S + ((long)b * L + l) * L;
  f16* prow = P + ((long)b * L + l) * L;
  const int* mrow = mask + b * L;
  const int t = threadIdx.x;

  const float4 v = *(const float4*)(&srow[t * 4]);
  const int4 mk = *(const int4*)(&mrow[t * 4]);
  const float x0 = mk.x ? -1e30f : v.x;
  const float x1 = mk.y ? -1e30f : v.y;
  const float x2 = mk.z ? -1e30f : v.z;
  const float x3 = mk.w ? -1e30f : v.w;

  float mx = fmaxf(fmaxf(x0, x1), fmaxf(x2, x3));
  #pragma unroll
  for (int off = 32; off >= 1; off >>= 1)
    mx = fmaxf(mx, __shfl_xor(mx, off));
  __shared__ float red[8];
  const int wid = t >> 6, lane = t & 63;
  if (lane == 0) red[wid] = mx;
  __syncthreads();
  mx = fmaxf(fmaxf(red[0], red[1]), fmaxf(red[2], red[3]));

  const float e0 = __expf(x0 - mx), e1 = __expf(x1 - mx);
  const float e2 = __expf(x2 - mx), e3 = __expf(x3 - mx);
  float s = e0 + e1 + e2 + e3;
  #pragma unroll
  for (int off = 32; off >= 1; off >>= 1)
    s += __shfl_xor(s, off);
  if (lane == 0) red[4 + wid] = s;
  __syncthreads();
  s = red[4] + red[5] + red[6] + red[7];
  const float inv = 1.f / s;
  half4 h;
  h[0] = (f16)(e0 * inv); h[1] = (f16)(e1 * inv);
  h[2] = (f16)(e2 * inv); h[3] = (f16)(e3 * inv);
  *(half4*)(&prow[t * 4]) = h;
}

extern "C" void kernel_launch(void* const* d_in, const int* in_sizes, int n_in,
                              void* d_out, int out_size, void* d_ws,
                              size_t ws_size, hipStream_t stream) {
  const float* x = (const float*)d_in[0];
  const float* y = (const float*)d_in[1];
  const int* ymask = (const int*)d_in[2];
  const float* W = (const float*)d_in[3];
  const float* bias = (const float*)d_in[4];
  float* out = (float*)d_out;

  // ws layout (162 MB):
  //   Wh 2MB | Yt 32MB | XYp 64MB | XYh 64MB (aliased by Sc after proj)
  char* ws = (char*)d_ws;
  f16* Wh = (f16*)(ws);
  f16* Yt = (f16*)(ws + (1L << 21));
  f16* XYp = (f16*)(ws + (1L << 21) + (1L << 25));
  f16* XYh = (f16*)(ws + (1L << 21) + (1L << 25) + (1L << 26));
  float* Sc = (float*)XYh;  // XYh dead after proj GEMM
  f16* Alpha = XYp;         // Xp half dead after scores GEMM

  f16* Xh = XYh;                        // rows [0, 16384)
  f16* Yh = XYh + (long)BATCH * L * H;  // rows [16384, 32768)

  cvt_f32_f16<<<512, 256, 0, stream>>>(W, Wh, (long)H * H);
  cvt_f32_f16<<<8192, 256, 0, stream>>>(x, Xh, (long)BATCH * L * H);
  transpose_y<<<dim3(32, 32, BATCH), dim3(32, 8), 0, stream>>>(y, Yh, Yt);

  // fused projection: [32768,1024] = relu(XYh @ Wh^T + b), fp16
  gemm256<0><<<512, 512, 0, stream>>>(XYh, Wh, bias, XYp, 0, 0, 0, 9);

  // scores[b] = Xp[b] @ Yp[b]^T, f32
  gemm256<1><<<256, 512, 0, stream>>>(XYp, XYp + (long)BATCH * L * H, nullptr,
                                      Sc, (long)L * H, (long)L * H,
                                      (long)L * L, 4);

  // alpha = softmax(mask(scores)), fp16 (into dead Xp region)
  softmax_rows<<<dim3(L, BATCH), 256, 0, stream>>>(Sc, ymask, Alpha);

  // out[b] = alpha[b] @ Yt[b]^T  == alpha[b] @ y[b]
  gemm256<1><<<256, 512, 0, stream>>>(Alpha, Yt, nullptr, out, (long)L * L,
                                      (long)H * L, (long)L * H, 4);
}

// Round 4
// 242.136 us; speedup vs baseline: 1.4193x; 1.0016x over previous
//
#include <hip/hip_runtime.h>
#include <hip/hip_fp16.h>

typedef _Float16 f16;
typedef _Float16 half4 __attribute__((ext_vector_type(4)));
typedef _Float16 half8 __attribute__((ext_vector_type(8)));
typedef float f32x4 __attribute__((ext_vector_type(4)));

#define BATCH 16
#define L 1024
#define H 1024

// ---------------- f32 -> fp16 bulk convert (8 elems/thread) ----------------
__global__ __launch_bounds__(256) void cvt_f32_f16(const float* __restrict__ in,
                                                   f16* __restrict__ out, long n) {
  long i = ((long)blockIdx.x * 256 + threadIdx.x) * 8;
  const long stride = (long)gridDim.x * 256 * 8;
  for (; i < n; i += stride) {
    const float4 a = *(const float4*)(&in[i]);
    const float4 b = *(const float4*)(&in[i + 4]);
    half8 h;
    h[0] = (f16)a.x; h[1] = (f16)a.y; h[2] = (f16)a.z; h[3] = (f16)a.w;
    h[4] = (f16)b.x; h[5] = (f16)b.y; h[6] = (f16)b.z; h[7] = (f16)b.w;
    *(half8*)(&out[i]) = h;
  }
}

// ------- y [b,m,h] f32 -> Yh [b,m,h] fp16 AND Yt [b,h,m] fp16 -------
__global__ __launch_bounds__(256) void transpose_y(const float* __restrict__ Y,
                                                   f16* __restrict__ Yh,
                                                   f16* __restrict__ Yt) {
  __shared__ f16 tile[32][33];
  const int b = blockIdx.z;
  const float* Yb = Y + (long)b * L * H;
  f16* Yhb = Yh + (long)b * L * H;
  f16* Ytb = Yt + (long)b * L * H;
  const int h0 = blockIdx.x * 32, m0 = blockIdx.y * 32;
  const int tx = threadIdx.x, ty = threadIdx.y;
  #pragma unroll
  for (int i = ty; i < 32; i += 8) {
    const f16 hv = (f16)Yb[(long)(m0 + i) * H + h0 + tx];
    tile[i][tx] = hv;
    Yhb[(long)(m0 + i) * H + h0 + tx] = hv;
  }
  __syncthreads();
  #pragma unroll
  for (int i = ty; i < 32; i += 8)
    Ytb[(long)(h0 + i) * L + m0 + tx] = tile[tx][i];
}

// =====================================================================
// 256x256 tile GEMM, BK=32, 8 waves, QUAD-buffered LDS (128KB), counted
// vmcnt, ONE barrier per K-tile.  C[M,1024] = A[M,1024] * B[1024,1024]^T.
// Per tile t: issue 4 gload_lds (tile t+3 -> buf (t+3)&3) | 12 ds_read
// | setprio1 | 32 MFMA | setprio0 | vmcnt(8) | barrier.
// vmcnt(8): waits only tile t+1's 4 loads, issued during t-2 (two full
// tile-times ago). Buf (t+3)&3 was last read during t-1; the t-1/t
// boundary barrier orders those reads (lgkmcnt(0) forced by MFMA deps)
// before this tile's rewrite. Tail: vmcnt 8 -> 4 -> 0.
// =====================================================================
constexpr int TBK = 32;

#define GLD16(g, l)                                           \
  __builtin_amdgcn_global_load_lds(                           \
      (const __attribute__((address_space(1))) void*)(g),     \
      (__attribute__((address_space(3))) void*)(l), 16, 0, 0)

template <int EPI>
__global__ __launch_bounds__(512, 2) void gemm256(
    const f16* __restrict__ Ap, const f16* __restrict__ Bp,
    const float* __restrict__ bias, void* __restrict__ Cp,
    long sA, long sB, long sC, int nxyShift) {
  __shared__ f16 lds[4 * 16384];  // 4 bufs x (A 16KB + B 16KB) = 128 KB
  constexpr int N = 1024, K = 1024, NT = K / TBK;

  const int tid = threadIdx.x;
  const int lane = tid & 63;
  const int wid = tid >> 6;   // 0..7
  const int wm = wid >> 2;    // 0..1  (M half)
  const int wn = wid & 3;     // 0..3  (N quarter)

  // XCD-aware bijective swizzle (nwg % 8 == 0 for all launches)
  const int nwg = gridDim.x;
  const int orig = blockIdx.x;
  const int wg = (orig & 7) * (nwg >> 3) + (orig >> 3);
  const int bz = wg >> nxyShift;
  const int rxy = wg & ((1 << nxyShift) - 1);
  const int bx = rxy & 3;      // N=1024 -> 4 col blocks
  const int by = rxy >> 2;
  const int row0 = by * 256, col0 = bx * 256;

  const f16* A = Ap + (long)bz * sA;
  const f16* B = Bp + (long)bz * sB;

  // ---- staging addressing (chunk = 16 rows x 64B = 1KB) ----
  const int srow = lane >> 2;                       // row in chunk
  const int sslot = (lane & 3) ^ ((lane >> 3) & 3); // pre-swizzled src slot
  const int ca0 = wid * 2, ca1 = wid * 2 + 1;       // this wave's chunks
  const f16* gA0 = A + (long)(row0 + ca0 * 16 + srow) * K + sslot * 8;
  const f16* gA1 = A + (long)(row0 + ca1 * 16 + srow) * K + sslot * 8;
  const f16* gB0 = B + (long)(col0 + ca0 * 16 + srow) * K + sslot * 8;
  const f16* gB1 = B + (long)(col0 + ca1 * 16 + srow) * K + sslot * 8;
  char* ldsw = (char*)lds;

  // ---- fragment read addressing (read-side XOR matches staging) ----
  const int fr = lane & 15, fq = lane >> 4;
  const int rsw = (fq ^ ((fr >> 1) & 3)) << 4;      // swizzled 16B slot
  const int aByte = (wm * 128 + fr) * 64 + rsw;
  const int bByte = (wn * 64 + fr) * 64 + rsw;
  const char* ldsr = (const char*)lds;

  f32x4 acc[8][4];
  #pragma unroll
  for (int i = 0; i < 8; ++i)
    #pragma unroll
    for (int j = 0; j < 4; ++j)
      acc[i][j] = (f32x4){0.f, 0.f, 0.f, 0.f};

  // ---- prologue: stage tiles 0,1,2 -> bufs 0,1,2 ----
  #pragma unroll
  for (int p = 0; p < 3; ++p) {
    char* b = ldsw + p * 32768;
    GLD16(gA0, b + ca0 * 1024);
    GLD16(gA1, b + ca1 * 1024);
    GLD16(gB0, b + 16384 + ca0 * 1024);
    GLD16(gB1, b + 16384 + ca1 * 1024);
    gA0 += TBK; gA1 += TBK; gB0 += TBK; gB1 += TBK;
  }
  asm volatile("s_waitcnt vmcnt(8)" ::: "memory");
  __builtin_amdgcn_s_barrier();
  __builtin_amdgcn_sched_barrier(0);

  for (int t = 0; t < NT; ++t) {
    // ---- issue prefetch for tile t+3 ----
    if (t + 3 < NT) {
      char* b = ldsw + ((t + 3) & 3) * 32768;
      GLD16(gA0, b + ca0 * 1024);
      GLD16(gA1, b + ca1 * 1024);
      GLD16(gB0, b + 16384 + ca0 * 1024);
      GLD16(gB1, b + 16384 + ca1 * 1024);
      gA0 += TBK; gA1 += TBK; gB0 += TBK; gB1 += TBK;
    }
    // ---- compute tile t from buf t&3 ----
    const char* base = ldsr + (t & 3) * 32768;
    half8 av[8], bv[4];
    #pragma unroll
    for (int j = 0; j < 4; ++j)
      bv[j] = *(const half8*)(base + 16384 + bByte + j * 1024);
    #pragma unroll
    for (int i = 0; i < 8; ++i)
      av[i] = *(const half8*)(base + aByte + i * 1024);
    __builtin_amdgcn_s_setprio(1);
    #pragma unroll
    for (int i = 0; i < 8; ++i)
      #pragma unroll
      for (int j = 0; j < 4; ++j)
        acc[i][j] = __builtin_amdgcn_mfma_f32_16x16x32_f16(av[i], bv[j],
                                                           acc[i][j], 0, 0, 0);
    __builtin_amdgcn_s_setprio(0);
    // ---- boundary: counted drain + single barrier ----
    if (t < NT - 1) {
      __builtin_amdgcn_sched_barrier(0);
      const int rem = NT - 1 - t;
      if (rem >= 3)
        asm volatile("s_waitcnt vmcnt(8)" ::: "memory");
      else if (rem == 2)
        asm volatile("s_waitcnt vmcnt(4)" ::: "memory");
      else
        asm volatile("s_waitcnt vmcnt(0)" ::: "memory");
      __builtin_amdgcn_s_barrier();
      __builtin_amdgcn_sched_barrier(0);
    }
  }

  // ---------------- epilogue ----------------
  if (EPI == 0) {
    f16* C = (f16*)Cp + (long)bz * sC;
    #pragma unroll
    for (int j = 0; j < 4; ++j) {
      const int col = col0 + wn * 64 + j * 16 + fr;
      const float bvs = bias[col];
      #pragma unroll
      for (int i = 0; i < 8; ++i) {
        const int rowb = row0 + wm * 128 + i * 16 + fq * 4;
        #pragma unroll
        for (int r = 0; r < 4; ++r) {
          float v = acc[i][j][r] + bvs;
          v = v > 0.f ? v : 0.f;
          C[(long)(rowb + r) * N + col] = (f16)v;
        }
      }
    }
  } else {
    float* C = (float*)Cp + (long)bz * sC;
    #pragma unroll
    for (int j = 0; j < 4; ++j) {
      const int col = col0 + wn * 64 + j * 16 + fr;
      #pragma unroll
      for (int i = 0; i < 8; ++i) {
        const int rowb = row0 + wm * 128 + i * 16 + fq * 4;
        #pragma unroll
        for (int r = 0; r < 4; ++r)
          C[(long)(rowb + r) * N + col] = acc[i][j][r];
      }
    }
  }
}

// ---------------- masked row softmax: f32 scores -> fp16 alpha ----------------
__global__ __launch_bounds__(256) void softmax_rows(const float* __restrict__ S,
                                                    const int* __restrict__ mask,
                                                    f16* __restrict__ P) {
  const int b = blockIdx.y;
  const int l = blockIdx.x;
  const float* srow = S + ((long)b * L + l) * L;
  f16* prow = P + ((long)b * L + l) * L;
  const int* mrow = mask + b * L;
  const int t = threadIdx.x;

  const float4 v = *(const float4*)(&srow[t * 4]);
  const int4 mk = *(const int4*)(&mrow[t * 4]);
  const float x0 = mk.x ? -1e30f : v.x;
  const float x1 = mk.y ? -1e30f : v.y;
  const float x2 = mk.z ? -1e30f : v.z;
  const float x3 = mk.w ? -1e30f : v.w;

  float mx = fmaxf(fmaxf(x0, x1), fmaxf(x2, x3));
  #pragma unroll
  for (int off = 32; off >= 1; off >>= 1)
    mx = fmaxf(mx, __shfl_xor(mx, off));
  __shared__ float red[8];
  const int wid = t >> 6, lane = t & 63;
  if (lane == 0) red[wid] = mx;
  __syncthreads();
  mx = fmaxf(fmaxf(red[0], red[1]), fmaxf(red[2], red[3]));

  const float e0 = __expf(x0 - mx), e1 = __expf(x1 - mx);
  const float e2 = __expf(x2 - mx), e3 = __expf(x3 - mx);
  float s = e0 + e1 + e2 + e3;
  #pragma unroll
  for (int off = 32; off >= 1; off >>= 1)
    s += __shfl_xor(s, off);
  if (lane == 0) red[4 + wid] = s;
  __syncthreads();
  s = red[4] + red[5] + red[6] + red[7];
  const float inv = 1.f / s;
  half4 h;
  h[0] = (f16)(e0 * inv); h[1] = (f16)(e1 * inv);
  h[2] = (f16)(e2 * inv); h[3] = (f16)(e3 * inv);
  *(half4*)(&prow[t * 4]) = h;
}

extern "C" void kernel_launch(void* const* d_in, const int* in_sizes, int n_in,
                              void* d_out, int out_size, void* d_ws,
                              size_t ws_size, hipStream_t stream) {
  const float* x = (const float*)d_in[0];
  const float* y = (const float*)d_in[1];
  const int* ymask = (const int*)d_in[2];
  const float* W = (const float*)d_in[3];
  const float* bias = (const float*)d_in[4];
  float* out = (float*)d_out;

  // ws layout (162 MB):
  //   Wh 2MB | Yt 32MB | XYp 64MB | XYh 64MB (aliased by Sc after proj)
  char* ws = (char*)d_ws;
  f16* Wh = (f16*)(ws);
  f16* Yt = (f16*)(ws + (1L << 21));
  f16* XYp = (f16*)(ws + (1L << 21) + (1L << 25));
  f16* XYh = (f16*)(ws + (1L << 21) + (1L << 25) + (1L << 26));
  float* Sc = (float*)XYh;  // XYh dead after proj GEMM
  f16* Alpha = XYp;         // Xp half dead after scores GEMM

  f16* Xh = XYh;                        // rows [0, 16384)
  f16* Yh = XYh + (long)BATCH * L * H;  // rows [16384, 32768)

  cvt_f32_f16<<<512, 256, 0, stream>>>(W, Wh, (long)H * H);
  cvt_f32_f16<<<8192, 256, 0, stream>>>(x, Xh, (long)BATCH * L * H);
  transpose_y<<<dim3(32, 32, BATCH), dim3(32, 8), 0, stream>>>(y, Yh, Yt);

  // fused projection: [32768,1024] = relu(XYh @ Wh^T + b), fp16
  gemm256<0><<<512, 512, 0, stream>>>(XYh, Wh, bias, XYp, 0, 0, 0, 9);

  // scores[b] = Xp[b] @ Yp[b]^T, f32
  gemm256<1><<<256, 512, 0, stream>>>(XYp, XYp + (long)BATCH * L * H, nullptr,
                                      Sc, (long)L * H, (long)L * H,
                                      (long)L * L, 4);

  // alpha = softmax(mask(scores)), fp16 (into dead Xp region)
  softmax_rows<<<dim3(L, BATCH), 256, 0, stream>>>(Sc, ymask, Alpha);

  // out[b] = alpha[b] @ Yt[b]^T  == alpha[b] @ y[b]
  gemm256<1><<<256, 512, 0, stream>>>(Alpha, Yt, nullptr, out, (long)L * L,
                                      (long)H * L, (long)L * H, 4);
}

// Round 5
// 236.581 us; speedup vs baseline: 1.4526x; 1.0235x over previous
//
#include <hip/hip_runtime.h>
#include <hip/hip_fp16.h>

typedef _Float16 f16;
typedef _Float16 half4 __attribute__((ext_vector_type(4)));
typedef _Float16 half8 __attribute__((ext_vector_type(8)));
typedef float f32x4 __attribute__((ext_vector_type(4)));

#define BATCH 16
#define L 1024
#define H 1024

// ---------------- f32 -> fp16 bulk convert (8 elems/thread) ----------------
__global__ __launch_bounds__(256) void cvt_f32_f16(const float* __restrict__ in,
                                                   f16* __restrict__ out, long n) {
  long i = ((long)blockIdx.x * 256 + threadIdx.x) * 8;
  const long stride = (long)gridDim.x * 256 * 8;
  for (; i < n; i += stride) {
    const float4 a = *(const float4*)(&in[i]);
    const float4 b = *(const float4*)(&in[i + 4]);
    half8 h;
    h[0] = (f16)a.x; h[1] = (f16)a.y; h[2] = (f16)a.z; h[3] = (f16)a.w;
    h[4] = (f16)b.x; h[5] = (f16)b.y; h[6] = (f16)b.z; h[7] = (f16)b.w;
    *(half8*)(&out[i]) = h;
  }
}

// ------- y [b,m,h] f32 -> Yh [b,m,h] fp16 AND Yt [b,h,m] fp16 -------
__global__ __launch_bounds__(256) void transpose_y(const float* __restrict__ Y,
                                                   f16* __restrict__ Yh,
                                                   f16* __restrict__ Yt) {
  __shared__ f16 tile[32][33];
  const int b = blockIdx.z;
  const float* Yb = Y + (long)b * L * H;
  f16* Yhb = Yh + (long)b * L * H;
  f16* Ytb = Yt + (long)b * L * H;
  const int h0 = blockIdx.x * 32, m0 = blockIdx.y * 32;
  const int tx = threadIdx.x, ty = threadIdx.y;
  #pragma unroll
  for (int i = ty; i < 32; i += 8) {
    const f16 hv = (f16)Yb[(long)(m0 + i) * H + h0 + tx];
    tile[i][tx] = hv;
    Yhb[(long)(m0 + i) * H + h0 + tx] = hv;
  }
  __syncthreads();
  #pragma unroll
  for (int i = ty; i < 32; i += 8)
    Ytb[(long)(h0 + i) * L + m0 + tx] = tile[tx][i];
}

// =====================================================================
// 256x128 tile GEMM, BK=32, 8 waves (wm 0..3 x wn 0..1, 64x64/wave),
// 3-slot LDS (72KB) -> 2 blocks/CU for cross-block phase overlap.
// C[M,1024] = A[M,1024] * B[1024,1024]^T, fp16 in.
// Per K-32 step t: issue 3 gload_lds (step t+2 -> slot (t+2)%3) |
// 8 ds_read_b128 | setprio1 | 16 MFMA | setprio0 | vmcnt(3) | barrier.
// Slot (t+2)%3 held step t-1, whose reads finished before the t-1/t
// barrier -> rewrite safe. vmcnt(3) leaves step t+2's 3 loads in
// flight, guarantees step t+1 landed. Tail: t=30 -> vmcnt(0).
// =====================================================================
#define GLD16(g, l)                                           \
  __builtin_amdgcn_global_load_lds(                           \
      (const __attribute__((address_space(1))) void*)(g),     \
      (__attribute__((address_space(3))) void*)(l), 16, 0, 0)

template <int EPI, int TAG>
__global__ __launch_bounds__(512, 4) void gemm128(
    const f16* __restrict__ Ap, const f16* __restrict__ Bp,
    const float* __restrict__ bias, void* __restrict__ Cp,
    long sA, long sB, long sC, int nxyShift) {
  __shared__ f16 lds[3 * 12288];  // 3 slots x (A 16KB + B 8KB) = 72 KB
  constexpr int N = 1024, K = 1024, NT = 32;

  const int tid = threadIdx.x;
  const int lane = tid & 63;
  const int wid = tid >> 6;   // 0..7
  const int wm = wid >> 1;    // 0..3  (64-row band)
  const int wn = wid & 1;     // 0..1  (64-col band)

  // XCD-aware bijective swizzle (nwg % 8 == 0 for all launches)
  const int nwg = gridDim.x;
  const int orig = blockIdx.x;
  const int wg = (orig & 7) * (nwg >> 3) + (orig >> 3);
  const int bz = wg >> nxyShift;
  const int rxy = wg & ((1 << nxyShift) - 1);
  const int bx = rxy & 7;      // N=1024 -> 8 col blocks of 128
  const int by = rxy >> 3;
  const int row0 = by * 256, col0 = bx * 128;

  const f16* A = Ap + (long)bz * sA;
  const f16* B = Bp + (long)bz * sB;

  // ---- staging addressing (chunk = 16 rows x 64B = 1KB) ----
  const int srow = lane >> 2;                       // row in chunk
  const int sslot = (lane & 3) ^ ((lane >> 3) & 3); // pre-swizzled src slot
  // wave stages A chunks {2w,2w+1} (rows 32w..32w+31), B chunk w
  const f16* gA0 = A + (long)(row0 + wid * 32 + srow) * K + sslot * 8;
  const f16* gA1 = A + (long)(row0 + wid * 32 + 16 + srow) * K + sslot * 8;
  const f16* gB0 = B + (long)(col0 + wid * 16 + srow) * K + sslot * 8;
  char* ldsw = (char*)lds;

  // ---- fragment read addressing (read-side XOR matches staging) ----
  const int fr = lane & 15, fq = lane >> 4;
  const int rsw = (fq ^ ((fr >> 1) & 3)) << 4;      // swizzled 16B slot
  const int aByte = (wm * 64 + fr) * 64 + rsw;
  const int bByte = (wn * 64 + fr) * 64 + rsw;
  const char* ldsr = (const char*)lds;

  f32x4 acc[4][4];
  #pragma unroll
  for (int i = 0; i < 4; ++i)
    #pragma unroll
    for (int j = 0; j < 4; ++j)
      acc[i][j] = (f32x4){0.f, 0.f, 0.f, 0.f};

  // ---- prologue: stage steps 0,1 -> slots 0,1 ----
  #pragma unroll
  for (int p = 0; p < 2; ++p) {
    char* sb = ldsw + p * 24576;
    GLD16(gA0, sb + wid * 2048);
    GLD16(gA1, sb + wid * 2048 + 1024);
    GLD16(gB0, sb + 16384 + wid * 1024);
    gA0 += 32; gA1 += 32; gB0 += 32;
  }
  asm volatile("s_waitcnt vmcnt(3)" ::: "memory");
  __builtin_amdgcn_s_barrier();
  __builtin_amdgcn_sched_barrier(0);

  int cb = 0, pb = 2 * 24576;
  for (int t = 0; t < NT; ++t) {
    // ---- issue prefetch for step t+2 ----
    if (t + 2 < NT) {
      char* sb = ldsw + pb;
      GLD16(gA0, sb + wid * 2048);
      GLD16(gA1, sb + wid * 2048 + 1024);
      GLD16(gB0, sb + 16384 + wid * 1024);
      gA0 += 32; gA1 += 32; gB0 += 32;
    }
    // ---- compute step t from slot t%3 ----
    const char* base = ldsr + cb;
    half8 av[4], bv[4];
    #pragma unroll
    for (int j = 0; j < 4; ++j)
      bv[j] = *(const half8*)(base + 16384 + bByte + j * 1024);
    #pragma unroll
    for (int i = 0; i < 4; ++i)
      av[i] = *(const half8*)(base + aByte + i * 1024);
    __builtin_amdgcn_s_setprio(1);
    #pragma unroll
    for (int i = 0; i < 4; ++i)
      #pragma unroll
      for (int j = 0; j < 4; ++j)
        acc[i][j] = __builtin_amdgcn_mfma_f32_16x16x32_f16(av[i], bv[j],
                                                           acc[i][j], 0, 0, 0);
    __builtin_amdgcn_s_setprio(0);
    // ---- boundary: counted drain + single barrier ----
    if (t < NT - 1) {
      __builtin_amdgcn_sched_barrier(0);
      if (t <= NT - 3)
        asm volatile("s_waitcnt vmcnt(3)" ::: "memory");
      else
        asm volatile("s_waitcnt vmcnt(0)" ::: "memory");
      __builtin_amdgcn_s_barrier();
      __builtin_amdgcn_sched_barrier(0);
      cb = (cb == 49152) ? 0 : cb + 24576;
      pb = (pb == 49152) ? 0 : pb + 24576;
    }
  }

  // ---------------- epilogue ----------------
  if (EPI == 0) {
    f16* C = (f16*)Cp + (long)bz * sC;
    #pragma unroll
    for (int j = 0; j < 4; ++j) {
      const int col = col0 + wn * 64 + j * 16 + fr;
      const float bvs = bias[col];
      #pragma unroll
      for (int i = 0; i < 4; ++i) {
        const int rowb = row0 + wm * 64 + i * 16 + fq * 4;
        #pragma unroll
        for (int r = 0; r < 4; ++r) {
          float v = acc[i][j][r] + bvs;
          v = v > 0.f ? v : 0.f;
          C[(long)(rowb + r) * N + col] = (f16)v;
        }
      }
    }
  } else {
    float* C = (float*)Cp + (long)bz * sC;
    #pragma unroll
    for (int j = 0; j < 4; ++j) {
      const int col = col0 + wn * 64 + j * 16 + fr;
      #pragma unroll
      for (int i = 0; i < 4; ++i) {
        const int rowb = row0 + wm * 64 + i * 16 + fq * 4;
        #pragma unroll
        for (int r = 0; r < 4; ++r)
          C[(long)(rowb + r) * N + col] = acc[i][j][r];
      }
    }
  }
}

// ---------------- masked row softmax: f32 scores -> fp16 alpha ----------------
__global__ __launch_bounds__(256) void softmax_rows(const float* __restrict__ S,
                                                    const int* __restrict__ mask,
                                                    f16* __restrict__ P) {
  const int b = blockIdx.y;
  const int l = blockIdx.x;
  const float* srow = S + ((long)b * L + l) * L;
  f16* prow = P + ((long)b * L + l) * L;
  const int* mrow = mask + b * L;
  const int t = threadIdx.x;

  const float4 v = *(const float4*)(&srow[t * 4]);
  const int4 mk = *(const int4*)(&mrow[t * 4]);
  const float x0 = mk.x ? -1e30f : v.x;
  const float x1 = mk.y ? -1e30f : v.y;
  const float x2 = mk.z ? -1e30f : v.z;
  const float x3 = mk.w ? -1e30f : v.w;

  float mx = fmaxf(fmaxf(x0, x1), fmaxf(x2, x3));
  #pragma unroll
  for (int off = 32; off >= 1; off >>= 1)
    mx = fmaxf(mx, __shfl_xor(mx, off));
  __shared__ float red[8];
  const int wid = t >> 6, lane = t & 63;
  if (lane == 0) red[wid] = mx;
  __syncthreads();
  mx = fmaxf(fmaxf(red[0], red[1]), fmaxf(red[2], red[3]));

  const float e0 = __expf(x0 - mx), e1 = __expf(x1 - mx);
  const float e2 = __expf(x2 - mx), e3 = __expf(x3 - mx);
  float s = e0 + e1 + e2 + e3;
  #pragma unroll
  for (int off = 32; off >= 1; off >>= 1)
    s += __shfl_xor(s, off);
  if (lane == 0) red[4 + wid] = s;
  __syncthreads();
  s = red[4] + red[5] + red[6] + red[7];
  const float inv = 1.f / s;
  half4 h;
  h[0] = (f16)(e0 * inv); h[1] = (f16)(e1 * inv);
  h[2] = (f16)(e2 * inv); h[3] = (f16)(e3 * inv);
  *(half4*)(&prow[t * 4]) = h;
}

extern "C" void kernel_launch(void* const* d_in, const int* in_sizes, int n_in,
                              void* d_out, int out_size, void* d_ws,
                              size_t ws_size, hipStream_t stream) {
  const float* x = (const float*)d_in[0];
  const float* y = (const float*)d_in[1];
  const int* ymask = (const int*)d_in[2];
  const float* W = (const float*)d_in[3];
  const float* bias = (const float*)d_in[4];
  float* out = (float*)d_out;

  // ws layout (162 MB):
  //   Wh 2MB | Yt 32MB | XYp 64MB | XYh 64MB (aliased by Sc after proj)
  char* ws = (char*)d_ws;
  f16* Wh = (f16*)(ws);
  f16* Yt = (f16*)(ws + (1L << 21));
  f16* XYp = (f16*)(ws + (1L << 21) + (1L << 25));
  f16* XYh = (f16*)(ws + (1L << 21) + (1L << 25) + (1L << 26));
  float* Sc = (float*)XYh;  // XYh dead after proj GEMM
  f16* Alpha = XYp;         // Xp half dead after scores GEMM

  f16* Xh = XYh;                        // rows [0, 16384)
  f16* Yh = XYh + (long)BATCH * L * H;  // rows [16384, 32768)

  cvt_f32_f16<<<512, 256, 0, stream>>>(W, Wh, (long)H * H);
  cvt_f32_f16<<<8192, 256, 0, stream>>>(x, Xh, (long)BATCH * L * H);
  transpose_y<<<dim3(32, 32, BATCH), dim3(32, 8), 0, stream>>>(y, Yh, Yt);

  // fused projection: [32768,1024] = relu(XYh @ Wh^T + b), fp16
  gemm128<0, 0><<<1024, 512, 0, stream>>>(XYh, Wh, bias, XYp, 0, 0, 0, 10);

  // scores[b] = Xp[b] @ Yp[b]^T, f32
  gemm128<1, 1><<<512, 512, 0, stream>>>(XYp, XYp + (long)BATCH * L * H,
                                         nullptr, Sc, (long)L * H, (long)L * H,
                                         (long)L * L, 5);

  // alpha = softmax(mask(scores)), fp16 (into dead Xp region)
  softmax_rows<<<dim3(L, BATCH), 256, 0, stream>>>(Sc, ymask, Alpha);

  // out[b] = alpha[b] @ Yt[b]^T  == alpha[b] @ y[b]
  gemm128<1, 2><<<512, 512, 0, stream>>>(Alpha, Yt, nullptr, out, (long)L * L,
                                         (long)H * L, (long)L * H, 5);
}